// Round 1
// 1333.482 us; speedup vs baseline: 1.0600x; 1.0600x over previous
//
#include <hip/hip_runtime.h>

#define NN 50000
#define NE 800000
#define DD 128
#define LN_EPS 1e-5f

typedef __attribute__((ext_vector_type(8))) short v8s;    // 8 bf16
typedef __attribute__((ext_vector_type(4))) unsigned v4u; // same 16B as v8s
typedef __attribute__((ext_vector_type(4))) float f32x4;  // MFMA acc

union CvtHL { v4u u; v8s s; };

__device__ __forceinline__ float leakyf(float x){ return x > 0.f ? x : 0.05f*x; }
__device__ __forceinline__ short f2bf(float f){
  unsigned u = __float_as_uint(f);
  u = (u + 0x7fffu + ((u >> 16) & 1u)) >> 16;   // RNE
  return (short)u;
}
__device__ __forceinline__ float bf2f(unsigned short h){
  return __uint_as_float(((unsigned)h) << 16);
}
// HW RNE pack: low16 = bf16(a), high16 = bf16(b). 1 inst for 2 values.
__device__ __forceinline__ unsigned cvt_pk_bf16(float a, float b){
  unsigned r;
  asm("v_cvt_pk_bf16_f32 %0, %1, %2" : "=v"(r) : "v"(a), "v"(b));
  return r;
}
// [hi16(u0) | hi16(u1)<<16] in one v_perm_b32 (sel 0-3 = low src = u0)
__device__ __forceinline__ unsigned pack_hi16(unsigned u0, unsigned u1){
  return __builtin_amdgcn_perm(u1, u0, 0x07060302u);
}
// split fp32 -> {hi, lo}: hi = truncated top-16 (cheap), lo = RNE(residual).
__device__ __forceinline__ short2 f2bf2v(float v){
  unsigned u = __float_as_uint(v);
  short hi = (short)(u >> 16);
  float lo = v - __uint_as_float(u & 0xffff0000u);
  return make_short2(hi, f2bf(lo));
}

// ---------------------------------------------------------------------------
// Weight packing: fp32 W[K][128] -> bf16 hi/lo planes, [(k>>3)*128+n][k&7]
// ---------------------------------------------------------------------------
__global__ void pack_w_kernel(const float* __restrict__ W, short* __restrict__ Wh,
                              short* __restrict__ Wl, int K, int Kp)
{
  int idx = blockIdx.x*256 + threadIdx.x;
  if (idx >= Kp*128) return;
  int k = idx >> 7, n = idx & 127;
  float v = (k < K) ? W[k*128 + n] : 0.f;
  short2 t = f2bf2v(v);
  size_t o = ((size_t)(k >> 3)*128 + n)*8 + (k & 7);
  Wh[o] = t.x; Wl[o] = t.y;
}

#define NPACK 11
struct PackArgs { const float* src[NPACK]; short* dh[NPACK]; short* dl[NPACK]; };

// all-K=128 batch pack: grid (64, NPACK)
__global__ void pack_many_kernel(PackArgs pa)
{
  int m = blockIdx.y;
  int idx = blockIdx.x*256 + threadIdx.x;   // 0..16383
  int k = idx >> 7, n = idx & 127;
  float v = pa.src[m][k*128 + n];
  short2 t = f2bf2v(v);
  size_t o = ((size_t)(k >> 3)*128 + n)*8 + (k & 7);
  pa.dh[m][o] = t.x; pa.dl[m][o] = t.y;
}

// full split-split product (A has hi+lo)
#define MFMA3(ah, al, bh, bl, ac) \
  ac = __builtin_amdgcn_mfma_f32_16x16x32_bf16(al, bh, ac, 0,0,0); \
  ac = __builtin_amdgcn_mfma_f32_16x16x32_bf16(ah, bl, ac, 0,0,0); \
  ac = __builtin_amdgcn_mfma_f32_16x16x32_bf16(ah, bh, ac, 0,0,0);

// A exact-bf16 (no lo plane): 2 MFMAs
#define MFMA2(ah, bh, bl, ac) \
  ac = __builtin_amdgcn_mfma_f32_16x16x32_bf16(ah, bl, ac, 0,0,0); \
  ac = __builtin_amdgcn_mfma_f32_16x16x32_bf16(ah, bh, ac, 0,0,0);

// 8 fp32 -> hi-plane (v_perm pack) + lo-plane (cvt_pk RNE): ~24 VALU vs ~52
#define SPLIT8(f0, f1, h, l) { \
  unsigned u0=__float_as_uint(f0.x), u1=__float_as_uint(f0.y), u2=__float_as_uint(f0.z), u3=__float_as_uint(f0.w); \
  unsigned u4=__float_as_uint(f1.x), u5=__float_as_uint(f1.y), u6=__float_as_uint(f1.z), u7=__float_as_uint(f1.w); \
  CvtHL ch_, cl_; \
  ch_.u = (v4u){ pack_hi16(u0,u1), pack_hi16(u2,u3), pack_hi16(u4,u5), pack_hi16(u6,u7) }; \
  cl_.u = (v4u){ \
    cvt_pk_bf16(f0.x-__uint_as_float(u0&0xffff0000u), f0.y-__uint_as_float(u1&0xffff0000u)), \
    cvt_pk_bf16(f0.z-__uint_as_float(u2&0xffff0000u), f0.w-__uint_as_float(u3&0xffff0000u)), \
    cvt_pk_bf16(f1.x-__uint_as_float(u4&0xffff0000u), f1.y-__uint_as_float(u5&0xffff0000u)), \
    cvt_pk_bf16(f1.z-__uint_as_float(u6&0xffff0000u), f1.w-__uint_as_float(u7&0xffff0000u)) }; \
  h = ch_.s; l = cl_.s; }

// ---------------------------------------------------------------------------
// 3-layer MLP + LayerNorm. Layer-1 inputs and all weights hi/lo split;
// hidden activations single-bf16 (layers 2/3 use 2 MFMAs).
// SCATTER: layer-1 edge gather staged AND hi/lo-split by 128 parallel threads
// (latency-parallel, dedups conversion); seg-reduce staging in bf16 aliasing
// the act plane, dword-vectorized reduce tail.
// ---------------------------------------------------------------------------
template<int IN_W, bool SCATTER>
__global__ __launch_bounds__(256)
void mlp_mfma_kernel(const float* __restrict__ x, int nrows,
                     const short* __restrict__ W1h, const short* __restrict__ W1l,
                     const float* __restrict__ b1,
                     const short* __restrict__ W2h, const short* __restrict__ W2l,
                     const float* __restrict__ b2,
                     const short* __restrict__ W3h, const short* __restrict__ W3l,
                     const float* __restrict__ b3,
                     const float* __restrict__ g, const float* __restrict__ bb,
                     float* __restrict__ out,
                     const int* __restrict__ sidx,   // src-sorted src values
                     const int* __restrict__ eperm)  // sorted pos -> edge id
{
  constexpr int L1K = (IN_W + 31) / 32;
  __shared__ __align__(16) short Hh[128*136];   // act plane; reused (stride 132) as bf16 seg buffer
  __shared__ float lnS[128][2], lnQ[128][2];
  __shared__ int sidx_s[128];
  __shared__ __align__(16) uint4 xstage[SCATTER ? 128 : 1];  // pre-split hi/lo packs

  const int tid  = threadIdx.x;
  const int lane = tid & 63, wave = tid >> 6;
  const int wr = wave >> 1, wc = wave & 1;
  const int quad = lane >> 4, low = lane & 15;
  const int row0 = blockIdx.x * 128;

  if (SCATTER) {
    // 128 parallel scattered gathers + hi/lo split -> LDS stage
    if (tid < 128) {
      int e = eperm[row0 + tid];           // NE % 128 == 0
      float4 f = ((const float4*)x)[e];
      unsigned u0=__float_as_uint(f.x), u1=__float_as_uint(f.y);
      unsigned u2=__float_as_uint(f.z), u3=__float_as_uint(f.w);
      uint4 st;
      st.x = pack_hi16(u0,u1);
      st.y = pack_hi16(u2,u3);
      st.z = cvt_pk_bf16(f.x-__uint_as_float(u0&0xffff0000u), f.y-__uint_as_float(u1&0xffff0000u));
      st.w = cvt_pk_bf16(f.z-__uint_as_float(u2&0xffff0000u), f.w-__uint_as_float(u3&0xffff0000u));
      xstage[tid] = st;
      sidx_s[tid] = sidx[row0 + tid];
    }
    __syncthreads();
  }

  f32x4 acc[4][4];

  // ---------------- layer 1 (hi/lo A) ----------------
  #pragma unroll
  for (int tm=0;tm<4;tm++)
    #pragma unroll
    for (int tn=0;tn<4;tn++) acc[tm][tn] = (f32x4)0.f;

  for (int ks = 0; ks < L1K; ks++) {
    v8s ah[4], al[4], bh[4], bl[4];
    #pragma unroll
    for (int tm=0;tm<4;tm++) {
      int lr = wr*64 + tm*16 + low;
      v8s h = (v8s)0, l = (v8s)0;
      if (SCATTER && IN_W == 4) {
        if (quad == 0) {
          uint4 st = xstage[lr];
          CvtHL ch_, cl_;
          ch_.u = (v4u){ st.x, st.y, 0u, 0u };
          cl_.u = (v4u){ st.z, st.w, 0u, 0u };
          h = ch_.s; l = cl_.s;
        }
      } else if (IN_W % 32 == 0) {
        int r = row0 + lr;
        if (r < nrows) {
          const float* p = x + (size_t)r*IN_W + ks*32 + quad*8;
          float4 f0 = *(const float4*)p;
          float4 f1 = *(const float4*)(p + 4);
          SPLIT8(f0, f1, h, l);
        }
      } else {
        int r = row0 + lr;
        #pragma unroll
        for (int j=0;j<8;j++) {
          int k = ks*32 + quad*8 + j;
          if (k < IN_W && r < nrows) {
            short2 t = f2bf2v(x[(size_t)r*IN_W + k]);
            h[j] = t.x; l[j] = t.y;
          }
        }
      }
      ah[tm] = h; al[tm] = l;
    }
    #pragma unroll
    for (int tn=0;tn<4;tn++) {
      size_t o = ((size_t)(ks*4+quad)*128 + wc*64 + tn*16 + low)*8;
      bh[tn] = *(const v8s*)(W1h + o);
      bl[tn] = *(const v8s*)(W1l + o);
    }
    #pragma unroll
    for (int tm=0;tm<4;tm++)
      #pragma unroll
      for (int tn=0;tn<4;tn++) { MFMA3(ah[tm], al[tm], bh[tn], bl[tn], acc[tm][tn]); }
  }
  #pragma unroll
  for (int tn=0;tn<4;tn++) {
    float bv = b1[wc*64 + tn*16 + low];
    #pragma unroll
    for (int tm=0;tm<4;tm++) {
      unsigned p01 = cvt_pk_bf16(leakyf(acc[tm][tn][0]+bv), leakyf(acc[tm][tn][1]+bv));
      unsigned p23 = cvt_pk_bf16(leakyf(acc[tm][tn][2]+bv), leakyf(acc[tm][tn][3]+bv));
      int base = (wr*64+tm*16+quad*4)*136 + wc*64+tn*16+low;
      Hh[base]     = (short)p01;
      Hh[base+136] = (short)(p01>>16);
      Hh[base+272] = (short)p23;
      Hh[base+408] = (short)(p23>>16);
    }
  }
  __syncthreads();

  // ---------------- layer 2 (bf16 A from LDS, 2 MFMAs) ----------------
  #pragma unroll
  for (int tm=0;tm<4;tm++)
    #pragma unroll
    for (int tn=0;tn<4;tn++) acc[tm][tn] = (f32x4)0.f;
  #pragma unroll
  for (int ks=0;ks<4;ks++) {
    v8s ah[4], bh[4], bl[4];
    #pragma unroll
    for (int tm=0;tm<4;tm++)
      ah[tm] = *(const v8s*)&Hh[(wr*64+tm*16+low)*136 + ks*32 + quad*8];
    #pragma unroll
    for (int tn=0;tn<4;tn++) {
      size_t o = ((size_t)(ks*4+quad)*128 + wc*64 + tn*16 + low)*8;
      bh[tn] = *(const v8s*)(W2h + o);
      bl[tn] = *(const v8s*)(W2l + o);
    }
    #pragma unroll
    for (int tm=0;tm<4;tm++)
      #pragma unroll
      for (int tn=0;tn<4;tn++) { MFMA2(ah[tm], bh[tn], bl[tn], acc[tm][tn]); }
  }
  __syncthreads();
  #pragma unroll
  for (int tn=0;tn<4;tn++) {
    float bv = b2[wc*64 + tn*16 + low];
    #pragma unroll
    for (int tm=0;tm<4;tm++) {
      unsigned p01 = cvt_pk_bf16(leakyf(acc[tm][tn][0]+bv), leakyf(acc[tm][tn][1]+bv));
      unsigned p23 = cvt_pk_bf16(leakyf(acc[tm][tn][2]+bv), leakyf(acc[tm][tn][3]+bv));
      int base = (wr*64+tm*16+quad*4)*136 + wc*64+tn*16+low;
      Hh[base]     = (short)p01;
      Hh[base+136] = (short)(p01>>16);
      Hh[base+272] = (short)p23;
      Hh[base+408] = (short)(p23>>16);
    }
  }
  __syncthreads();

  // ---------------- layer 3 (bf16 A from LDS, 2 MFMAs) ----------------
  #pragma unroll
  for (int tm=0;tm<4;tm++)
    #pragma unroll
    for (int tn=0;tn<4;tn++) acc[tm][tn] = (f32x4)0.f;
  #pragma unroll
  for (int ks=0;ks<4;ks++) {
    v8s ah[4], bh[4], bl[4];
    #pragma unroll
    for (int tm=0;tm<4;tm++)
      ah[tm] = *(const v8s*)&Hh[(wr*64+tm*16+low)*136 + ks*32 + quad*8];
    #pragma unroll
    for (int tn=0;tn<4;tn++) {
      size_t o = ((size_t)(ks*4+quad)*128 + wc*64 + tn*16 + low)*8;
      bh[tn] = *(const v8s*)(W3h + o);
      bl[tn] = *(const v8s*)(W3l + o);
    }
    #pragma unroll
    for (int tm=0;tm<4;tm++)
      #pragma unroll
      for (int tn=0;tn<4;tn++) { MFMA2(ah[tm], bh[tn], bl[tn], acc[tm][tn]); }
  }
  #pragma unroll
  for (int tn=0;tn<4;tn++) {
    float bv = b3[wc*64 + tn*16 + low];
    #pragma unroll
    for (int tm=0;tm<4;tm++)
      #pragma unroll
      for (int i=0;i<4;i++) acc[tm][tn][i] += bv;
  }

  // ---------------- fused LayerNorm ----------------
  #pragma unroll
  for (int tm=0;tm<4;tm++)
    #pragma unroll
    for (int i=0;i<4;i++) {
      float s = acc[tm][0][i] + acc[tm][1][i] + acc[tm][2][i] + acc[tm][3][i];
      float q = acc[tm][0][i]*acc[tm][0][i] + acc[tm][1][i]*acc[tm][1][i]
              + acc[tm][2][i]*acc[tm][2][i] + acc[tm][3][i]*acc[tm][3][i];
      s += __shfl_xor(s, 1); q += __shfl_xor(q, 1);
      s += __shfl_xor(s, 2); q += __shfl_xor(q, 2);
      s += __shfl_xor(s, 4); q += __shfl_xor(q, 4);
      s += __shfl_xor(s, 8); q += __shfl_xor(q, 8);
      if (low == tm*4 + i) {
        int r = wr*64 + tm*16 + quad*4 + i;
        lnS[r][wc] = s; lnQ[r][wc] = q;
      }
    }
  __syncthreads();   // all layer-3 H reads done (act-plane reuse below is safe)

  float g4[4], bb4[4];
  #pragma unroll
  for (int tn=0;tn<4;tn++) { int c = wc*64+tn*16+low; g4[tn] = g[c]; bb4[tn] = bb[c]; }

  #pragma unroll
  for (int tm=0;tm<4;tm++)
    #pragma unroll
    for (int i=0;i<4;i++) {
      int r = wr*64 + tm*16 + quad*4 + i;
      float s = lnS[r][0] + lnS[r][1];
      float q = lnQ[r][0] + lnQ[r][1];
      float m = s * (1.f/128.f);
      float var = q * (1.f/128.f) - m*m;
      float rs = rsqrtf(var + LN_EPS);
      int gr = row0 + r;
      if (!SCATTER && gr >= nrows) continue;
      float v0 = (acc[tm][0][i] - m) * rs * g4[0] + bb4[0];
      float v1 = (acc[tm][1][i] - m) * rs * g4[1] + bb4[1];
      float v2 = (acc[tm][2][i] - m) * rs * g4[2] + bb4[2];
      float v3 = (acc[tm][3][i] - m) * rs * g4[3] + bb4[3];
      if (SCATTER) {
        unsigned p01 = cvt_pk_bf16(v0, v1), p23 = cvt_pk_bf16(v2, v3);
        int base = r*132 + wc*64 + low;
        Hh[base]    = (short)p01;      // bf16 stage for seg-reduce
        Hh[base+16] = (short)(p01>>16);
        Hh[base+32] = (short)p23;
        Hh[base+48] = (short)(p23>>16);
      } else {
        size_t ob = (size_t)gr*DD + wc*64 + low;
        out[ob]    = v0;
        out[ob+16] = v1;
        out[ob+32] = v2;
        out[ob+48] = v3;
      }
    }

  if (SCATTER) {
    __syncthreads();
    // dword-vectorized seg-reduce: wave g handles rows [g*32, g*32+32), 64 col-pairs
    const unsigned* H32 = (const unsigned*)Hh;    // row stride 66 dwords
    int cp = tid & 63;
    int gI = tid >> 6;
    int rbeg = gI*32, rend = rbeg + 32;
    unsigned pv = H32[rbeg*66 + cp];
    float a0 = __uint_as_float(pv << 16), a1 = __uint_as_float(pv & 0xffff0000u);
    int cur = sidx_s[rbeg];
    for (int r = rbeg + 1; r < rend; r++) {
      int sv = sidx_s[r];                          // wave-uniform
      unsigned hv = H32[r*66 + cp];
      if (sv != cur) {
        atomicAdd(&out[(size_t)cur*DD + 2*cp],     a0);
        atomicAdd(&out[(size_t)cur*DD + 2*cp + 1], a1);
        a0 = __uint_as_float(hv << 16); a1 = __uint_as_float(hv & 0xffff0000u);
        cur = sv;
      } else {
        a0 += __uint_as_float(hv << 16); a1 += __uint_as_float(hv & 0xffff0000u);
      }
    }
    atomicAdd(&out[(size_t)cur*DD + 2*cp],     a0);
    atomicAdd(&out[(size_t)cur*DD + 2*cp + 1], a1);
  }
}

// ---------------------------------------------------------------------------
// outbf[r] = bf16((x[r] @ W + initv) * rowscale[r])  — fp32 input (split, 3 MFMA)
// ---------------------------------------------------------------------------
__global__ __launch_bounds__(256)
void gemm_mfma_kernel(const float* __restrict__ x,
                      const short* __restrict__ Wh, const short* __restrict__ Wl,
                      const float* __restrict__ initv, const float* __restrict__ rowscale,
                      unsigned short* __restrict__ outbf, int nrows)
{
  const int tid  = threadIdx.x;
  const int lane = tid & 63, wave = tid >> 6;
  const int wr = wave >> 1, wc = wave & 1;
  const int quad = lane >> 4, low = lane & 15;
  const int row0 = blockIdx.x * 64;

  f32x4 acc[2][4];
  #pragma unroll
  for (int tm=0;tm<2;tm++)
    #pragma unroll
    for (int tn=0;tn<4;tn++) acc[tm][tn] = (f32x4)0.f;

  #pragma unroll
  for (int ks=0;ks<4;ks++) {
    v8s ah[2], al[2], bh[4], bl[4];
    #pragma unroll
    for (int tm=0;tm<2;tm++) {
      int r = row0 + wr*32 + tm*16 + low;
      v8s h = (v8s)0, l = (v8s)0;
      if (r < nrows) {
        const float* p = x + (size_t)r*DD + ks*32 + quad*8;
        float4 f0 = *(const float4*)p;
        float4 f1 = *(const float4*)(p + 4);
        SPLIT8(f0, f1, h, l);
      }
      ah[tm] = h; al[tm] = l;
    }
    #pragma unroll
    for (int tn=0;tn<4;tn++) {
      size_t o = ((size_t)(ks*4+quad)*128 + wc*64 + tn*16 + low)*8;
      bh[tn] = *(const v8s*)(Wh + o);
      bl[tn] = *(const v8s*)(Wl + o);
    }
    #pragma unroll
    for (int tm=0;tm<2;tm++)
      #pragma unroll
      for (int tn=0;tn<4;tn++) { MFMA3(ah[tm], al[tm], bh[tn], bl[tn], acc[tm][tn]); }
  }

  float iv4[4];
  #pragma unroll
  for (int tn=0;tn<4;tn++) iv4[tn] = initv ? initv[wc*64 + tn*16 + low] : 0.f;

  #pragma unroll
  for (int tm=0;tm<2;tm++)
    #pragma unroll
    for (int i=0;i<4;i++) {
      int gr = row0 + wr*32 + tm*16 + quad*4 + i;
      if (gr >= nrows) continue;
      float sc = rowscale ? rowscale[gr] : 1.f;
      float v0 = (acc[tm][0][i] + iv4[0]) * sc;
      float v1 = (acc[tm][1][i] + iv4[1]) * sc;
      float v2 = (acc[tm][2][i] + iv4[2]) * sc;
      float v3 = (acc[tm][3][i] + iv4[3]) * sc;
      unsigned p01 = cvt_pk_bf16(v0, v1), p23 = cvt_pk_bf16(v2, v3);
      size_t base = (size_t)gr*DD + wc*64 + low;
      outbf[base]    = (unsigned short)p01;
      outbf[base+16] = (unsigned short)(p01>>16);
      outbf[base+32] = (unsigned short)p23;
      outbf[base+48] = (unsigned short)(p23>>16);
    }
}

// ---------------------------------------------------------------------------
// Same but bf16 input (exact, 2 MFMA, 16 B/lane A-loads) — conv2 on y.
// ---------------------------------------------------------------------------
__global__ __launch_bounds__(256)
void gemm_bf_mfma_kernel(const unsigned short* __restrict__ xb,
                         const short* __restrict__ Wh, const short* __restrict__ Wl,
                         const float* __restrict__ initv, const float* __restrict__ rowscale,
                         unsigned short* __restrict__ outbf, int nrows)
{
  const int tid  = threadIdx.x;
  const int lane = tid & 63, wave = tid >> 6;
  const int wr = wave >> 1, wc = wave & 1;
  const int quad = lane >> 4, low = lane & 15;
  const int row0 = blockIdx.x * 64;

  f32x4 acc[2][4];
  #pragma unroll
  for (int tm=0;tm<2;tm++)
    #pragma unroll
    for (int tn=0;tn<4;tn++) acc[tm][tn] = (f32x4)0.f;

  #pragma unroll
  for (int ks=0;ks<4;ks++) {
    v8s ah[2], bh[4], bl[4];
    #pragma unroll
    for (int tm=0;tm<2;tm++) {
      int r = row0 + wr*32 + tm*16 + low;
      ah[tm] = (r < nrows) ? *(const v8s*)(xb + (size_t)r*DD + ks*32 + quad*8) : (v8s)0;
    }
    #pragma unroll
    for (int tn=0;tn<4;tn++) {
      size_t o = ((size_t)(ks*4+quad)*128 + wc*64 + tn*16 + low)*8;
      bh[tn] = *(const v8s*)(Wh + o);
      bl[tn] = *(const v8s*)(Wl + o);
    }
    #pragma unroll
    for (int tm=0;tm<2;tm++)
      #pragma unroll
      for (int tn=0;tn<4;tn++) { MFMA2(ah[tm], bh[tn], bl[tn], acc[tm][tn]); }
  }

  float iv4[4];
  #pragma unroll
  for (int tn=0;tn<4;tn++) iv4[tn] = initv ? initv[wc*64 + tn*16 + low] : 0.f;

  #pragma unroll
  for (int tm=0;tm<2;tm++)
    #pragma unroll
    for (int i=0;i<4;i++) {
      int gr = row0 + wr*32 + tm*16 + quad*4 + i;
      if (gr >= nrows) continue;
      float sc = rowscale ? rowscale[gr] : 1.f;
      float v0 = (acc[tm][0][i] + iv4[0]) * sc;
      float v1 = (acc[tm][1][i] + iv4[1]) * sc;
      float v2 = (acc[tm][2][i] + iv4[2]) * sc;
      float v3 = (acc[tm][3][i] + iv4[3]) * sc;
      unsigned p01 = cvt_pk_bf16(v0, v1), p23 = cvt_pk_bf16(v2, v3);
      size_t base = (size_t)gr*DD + wc*64 + low;
      outbf[base]    = (unsigned short)p01;
      outbf[base+16] = (unsigned short)(p01>>16);
      outbf[base+32] = (unsigned short)p23;
      outbf[base+48] = (unsigned short)(p23>>16);
    }
}

// ---------------------------------------------------------------------------
// GCN aggregation on bf16-packed pre-scaled h. One wave per node; unroll 16/4.
// wave id via readfirstlane so CSR walk is scalar (s_load + SALU addressing).
// mode 0: outb = bf16(leaky(agg))   mode 1: outf = resid + agg (fp32)
// ---------------------------------------------------------------------------
__global__ __launch_bounds__(256)
void gcn_agg_kernel(const unsigned* __restrict__ hb, const int* __restrict__ rowptr,
                    const int* __restrict__ csr_src, const float* __restrict__ dis,
                    const float* __restrict__ bias, const float* __restrict__ resid,
                    float* __restrict__ outf, unsigned* __restrict__ outb, int mode)
{
  const int wv = __builtin_amdgcn_readfirstlane(threadIdx.x >> 6);
  const int lane = threadIdx.x & 63;
  const int i = blockIdx.x*4 + wv;
  if (i >= NN) return;
  unsigned hv = hb[(size_t)i*64 + lane];
  float ax = bf2f((unsigned short)(hv & 0xffff)), ay = bf2f((unsigned short)(hv >> 16));
  const int beg = rowptr[i], end = rowptr[i+1];
  int j = beg;
  for (; j + 16 <= end; j += 16) {
    unsigned v[16];
    #pragma unroll
    for (int k=0;k<16;k++) v[k] = hb[(size_t)csr_src[j+k]*64 + lane];
    #pragma unroll
    for (int k=0;k<16;k++) {
      ax += bf2f((unsigned short)(v[k] & 0xffff));
      ay += bf2f((unsigned short)(v[k] >> 16));
    }
  }
  for (; j + 4 <= end; j += 4) {
    unsigned v[4];
    #pragma unroll
    for (int k=0;k<4;k++) v[k] = hb[(size_t)csr_src[j+k]*64 + lane];
    #pragma unroll
    for (int k=0;k<4;k++) {
      ax += bf2f((unsigned short)(v[k] & 0xffff));
      ay += bf2f((unsigned short)(v[k] >> 16));
    }
  }
  for (; j < end; j++) {
    unsigned v = hb[(size_t)csr_src[j]*64 + lane];
    ax += bf2f((unsigned short)(v & 0xffff));
    ay += bf2f((unsigned short)(v >> 16));
  }
  float di = dis[i];
  ax = ax*di + bias[2*lane]; ay = ay*di + bias[2*lane+1];
  size_t o = (size_t)i*64 + lane;
  if (mode == 0) {
    outb[o] = cvt_pk_bf16(leakyf(ax), leakyf(ay));
  } else {
    float2 rs = ((const float2*)resid)[o];
    float2 r; r.x = rs.x + ax; r.y = rs.y + ay;
    ((float2*)outf)[o] = r;
  }
}

// ---------------------------------------------------------------------------
// Graph setup
// ---------------------------------------------------------------------------
__global__ void count_kernel(const int* __restrict__ src, const int* __restrict__ dst,
                             int* __restrict__ cnt_src, int* __restrict__ deg_dst)
{
  int e = blockIdx.x*blockDim.x + threadIdx.x;
  if (e < NE) {
    atomicAdd(&cnt_src[src[e]], 1);
    atomicAdd(&deg_dst[dst[e]], 1);
  }
}

__global__ void nodeparams_kernel(const int* __restrict__ deg_dst, const int* __restrict__ cnt_src,
                                  float* __restrict__ dis, float* __restrict__ invcnt)
{
  int i = blockIdx.x*blockDim.x + threadIdx.x;
  if (i < NN) {
    dis[i] = rsqrtf((float)deg_dst[i] + 1.0f);
    invcnt[i] = 1.0f / fmaxf((float)cnt_src[i], 1.0f);
  }
}

// two independent single-block scans: block 0 = (a0->r0,n0), block 1 = (a1->r1,n1)
__global__ void scan2_kernel(const int* __restrict__ a0, int* __restrict__ r0, int* __restrict__ n0,
                             const int* __restrict__ a1, int* __restrict__ r1, int* __restrict__ n1)
{
  const int* a = blockIdx.x ? a1 : a0;
  int* r = blockIdx.x ? r1 : r0;
  int* n = blockIdx.x ? n1 : n0;
  const int T = 256;
  int tid = threadIdx.x;
  int chunk = (NN + T - 1) / T;
  int begin = tid*chunk, end = begin + chunk; if (end > NN) end = NN; if (begin > NN) begin = NN;
  int s = 0;
  for (int i = begin; i < end; i++) s += a[i];
  __shared__ int ps[T];
  ps[tid] = s; __syncthreads();
  for (int off = 1; off < T; off <<= 1) {
    int v = 0;
    if (tid >= off) v = ps[tid - off];
    __syncthreads();
    if (tid >= off) ps[tid] += v;
    __syncthreads();
  }
  int base = (tid == 0) ? 0 : ps[tid-1];
  for (int i = begin; i < end; i++) { r[i] = base; n[i] = base; base += a[i]; }
  if (tid == T-1) r[NN] = base;
}

__global__ void fill_kernel(const int* __restrict__ src, const int* __restrict__ dst,
                            int* __restrict__ nextp, int* __restrict__ csr_src)
{
  int e = blockIdx.x*blockDim.x + threadIdx.x;
  if (e < NE) {
    int pos = atomicAdd(&nextp[dst[e]], 1);
    csr_src[pos] = src[e];
  }
}

__global__ void fill_src_kernel(const int* __restrict__ src, int* __restrict__ nexts,
                                int* __restrict__ eperm, int* __restrict__ srcsorted)
{
  int e = blockIdx.x*blockDim.x + threadIdx.x;
  if (e < NE) {
    int s = src[e];
    int pos = atomicAdd(&nexts[s], 1);
    eperm[pos] = e;
    srcsorted[pos] = s;
  }
}

__global__ void addmean_kernel(float* __restrict__ hn, const float* __restrict__ nodesum,
                               const float* __restrict__ invcnt)
{
  int t = blockIdx.x*blockDim.x + threadIdx.x;
  if (t < NN*DD/4) {
    float4 a = ((const float4*)hn)[t];
    float4 b = ((const float4*)nodesum)[t];
    float ic = invcnt[t >> 5];
    a.x += b.x*ic; a.y += b.y*ic; a.z += b.z*ic; a.w += b.w*ic;
    ((float4*)hn)[t] = a;
  }
}

// ---------------------------------------------------------------------------
// BatchNorm stats (bf16 y) + parallel fold into packed hi/lo bf16 conv2 weight
// ---------------------------------------------------------------------------
__global__ __launch_bounds__(256)
void bn_stats_kernel(const unsigned short* __restrict__ yb, float* __restrict__ sums)
{
  int col = threadIdx.x & 127, grp = threadIdx.x >> 7;
  float s = 0.f, ss = 0.f;
  for (int i = blockIdx.x*2 + grp; i < NN; i += gridDim.x*2) {
    float v = bf2f(yb[(size_t)i*DD + col]);
    s += v; ss += v*v;
  }
  __shared__ float ls[256], lss[256];
  ls[threadIdx.x] = s; lss[threadIdx.x] = ss;
  __syncthreads();
  if (grp == 0) {
    atomicAdd(&sums[col],      ls[col]  + ls[col+128]);
    atomicAdd(&sums[DD + col], lss[col] + lss[col+128]);
  }
}

// grid = 16 blocks; block b handles k in [b*8, b*8+8). cvec pre-zeroed.
__global__ __launch_bounds__(256)
void bn_fold_kernel(const float* __restrict__ sums, const float* __restrict__ g,
                    const float* __restrict__ b, const float* __restrict__ W2,
                    short* __restrict__ Wfh, short* __restrict__ Wfl,
                    float* __restrict__ cvec)
{
  __shared__ float scale_s[DD], shift_s[DD];
  int tid = threadIdx.x;
  if (tid < DD) {
    float m = sums[tid] / (float)NN;
    float var = sums[DD + tid] / (float)NN - m*m;
    float is = rsqrtf(var + LN_EPS);
    float sc = is * g[tid];
    scale_s[tid] = sc;
    shift_s[tid] = b[tid] - m * sc;
  }
  __syncthreads();
  int col = tid & 127, kh = tid >> 7;   // kh = 0..1
  float cpart = 0.f;
  #pragma unroll
  for (int kk = 0; kk < 4; kk++) {
    int k = blockIdx.x*8 + kh*4 + kk;
    float w = W2[k*DD + col];
    short2 t = f2bf2v(w * scale_s[k]);
    size_t o = ((size_t)(k >> 3)*128 + col)*8 + (k & 7);
    Wfh[o] = t.x; Wfl[o] = t.y;
    cpart += shift_s[k] * w;
  }
  atomicAdd(&cvec[col], cpart);
}

// ---------------------------------------------------------------------------
extern "C" void kernel_launch(void* const* d_in, const int* in_sizes, int n_in,
                              void* d_out, int out_size, void* d_ws, size_t ws_size,
                              hipStream_t stream)
{
  const float* node_feat = (const float*)d_in[0];
  const float* edge_feat = (const float*)d_in[1];
  const int*   edge_index = (const int*)d_in[2];
  const int* src = edge_index;
  const int* dst = edge_index + NE;

  const float* enW1 = (const float*)d_in[3];  const float* enb1 = (const float*)d_in[4];
  const float* enW2 = (const float*)d_in[5];  const float* enb2 = (const float*)d_in[6];
  const float* enW3 = (const float*)d_in[7];  const float* enb3 = (const float*)d_in[8];
  const float* enlg = (const float*)d_in[9];  const float* enlb = (const float*)d_in[10];

  const float* eeW1 = (const float*)d_in[11]; const float* eeb1 = (const float*)d_in[12];
  const float* eeW2 = (const float*)d_in[13]; const float* eeb2 = (const float*)d_in[14];
  const float* eeW3 = (const float*)d_in[15]; const float* eeb3 = (const float*)d_in[16];
  const float* eelg = (const float*)d_in[17]; const float* eelb = (const float*)d_in[18];

  const float* procW = (const float*)d_in[19];
  const float* procB = (const float*)d_in[20];
  const float* bnG   = (const float*)d_in[21];
  const float* bnB   = (const float*)d_in[22];

  const float* dW1 = (const float*)d_in[23]; const float* db1 = (const float*)d_in[24];
  const float* dW2 = (const float*)d_in[25]; const float* db2 = (const float*)d_in[26];
  const float* dW3 = (const float*)d_in[27]; const float* db3 = (const float*)d_in[28];
  const float* dlg = (const float*)d_in[29]; const float* dlb = (const float*)d_in[30];

  char* ws = (char*)d_ws;
  size_t off = 0;
  auto alloc = [&](size_t bytes) -> void* {
    void* p = ws + off;
    off = (off + bytes + 255) & ~(size_t)255;
    return p;
  };
  float* hn     = (float*)alloc((size_t)NN*DD*4);
  float* esum   = (float*)alloc((size_t)NN*DD*4);   // edge scatter-sum accumulator
  unsigned short* hbf = (unsigned short*)alloc((size_t)NN*DD*2);  // bf16 gather table
  unsigned short* ybf = (unsigned short*)alloc((size_t)NN*DD*2);  // bf16 y (BN input)
  float* dis    = (float*)alloc(NN*4);
  float* invcnt = (float*)alloc(NN*4);
  float* bnsums = (float*)alloc(3*DD*4);   // [sum, sumsq, cvec]
  float* cvec   = bnsums + 2*DD;
  int* deg    = (int*)alloc(NN*4);
  int* cnt    = (int*)alloc(NN*4);
  int* rowptr = (int*)alloc((NN+1)*4);
  int* nextp  = (int*)alloc(NN*4);
  int* srow   = (int*)alloc((NN+1)*4);
  int* nexts  = (int*)alloc(NN*4);
  int* csr    = (int*)alloc((size_t)NE*4);
  int* eperm  = (int*)alloc((size_t)NE*4);
  int* srcsorted = (int*)alloc((size_t)NE*4);
  auto allocW = [&](int kp) { return (short*)alloc((size_t)kp*128*2); };
  short *pN1h=allocW(32),  *pN1l=allocW(32);
  short *pN2h=allocW(128), *pN2l=allocW(128);
  short *pN3h=allocW(128), *pN3l=allocW(128);
  short *pE1h=allocW(32),  *pE1l=allocW(32);
  short *pE2h=allocW(128), *pE2l=allocW(128);
  short *pE3h=allocW(128), *pE3l=allocW(128);
  short *pD1h=allocW(128), *pD1l=allocW(128);
  short *pD2h=allocW(128), *pD2l=allocW(128);
  short *pD3h=allocW(128), *pD3l=allocW(128);
  short *pP0h[5], *pP0l[5];
  for (int s = 0; s < 5; s++) { pP0h[s]=allocW(128); pP0l[s]=allocW(128); }
  short *pWfh=allocW(128), *pWfl=allocW(128);

  (void)hipMemsetAsync(deg, 0, NN*4, stream);
  (void)hipMemsetAsync(cnt, 0, NN*4, stream);
  (void)hipMemsetAsync(esum, 0, (size_t)NN*DD*4, stream);

  // pack static weights: 11 K=128 mats in one launch + 2 small ones
  PackArgs pa;
  const float* s128[NPACK] = { enW2, enW3, eeW2, eeW3, dW1, dW2, dW3,
                               procW + 0*(size_t)DD*DD*2, procW + 1*(size_t)DD*DD*2,
                               procW + 2*(size_t)DD*DD*2, procW + 3*(size_t)DD*DD*2 };
  short* d128h[NPACK] = { pN2h, pN3h, pE2h, pE3h, pD1h, pD2h, pD3h, pP0h[0], pP0h[1], pP0h[2], pP0h[3] };
  short* d128l[NPACK] = { pN2l, pN3l, pE2l, pE3l, pD1l, pD2l, pD3l, pP0l[0], pP0l[1], pP0l[2], pP0l[3] };
  for (int m = 0; m < NPACK; m++) { pa.src[m]=s128[m]; pa.dh[m]=d128h[m]; pa.dl[m]=d128l[m]; }
  pack_many_kernel<<<dim3(64, NPACK), 256, 0, stream>>>(pa);
  const int G32 = (32*128+255)/256, G128 = (128*128+255)/256;
  pack_w_kernel<<<G32, 256, 0, stream>>>(enW1, pN1h, pN1l, 19, 32);
  pack_w_kernel<<<G32, 256, 0, stream>>>(eeW1, pE1h, pE1l, 4, 32);
  pack_w_kernel<<<G128,256, 0, stream>>>(procW + 4*(size_t)DD*DD*2, pP0h[4], pP0l[4], 128, 128);

  // graph setup
  count_kernel<<<(NE+255)/256, 256, 0, stream>>>(src, dst, cnt, deg);
  nodeparams_kernel<<<(NN+255)/256, 256, 0, stream>>>(deg, cnt, dis, invcnt);
  scan2_kernel<<<2, 256, 0, stream>>>(deg, rowptr, nextp, cnt, srow, nexts);
  fill_kernel<<<(NE+255)/256, 256, 0, stream>>>(src, dst, nextp, csr);
  fill_src_kernel<<<(NE+255)/256, 256, 0, stream>>>(src, nexts, eperm, srcsorted);

  const int GN  = (NN + 127) / 128;  // 391
  const int GE  = NE / 128;          // 6250
  const int GG  = (NN + 63) / 64;    // 782
  const int GA  = (NN + 3) / 4;      // 12500

  // encoders
  mlp_mfma_kernel<19, false><<<GN, 256, 0, stream>>>(node_feat, NN,
      pN1h, pN1l, enb1, pN2h, pN2l, enb2, pN3h, pN3l, enb3, enlg, enlb, hn,
      nullptr, nullptr);
  mlp_mfma_kernel<4, true><<<GE, 256, 0, stream>>>(edge_feat, NE,
      pE1h, pE1l, eeb1, pE2h, pE2l, eeb2, pE3h, pE3l, eeb3, eelg, eelb, esum,
      srcsorted, eperm);
  addmean_kernel<<<(NN*DD/4+255)/256, 256, 0, stream>>>(hn, esum, invcnt);

  // processor: 5 residual (conv -> leaky -> BN -> conv) steps
  for (int s = 0; s < 5; s++) {
    const float* Wc2 = procW + (size_t)(s*2+1)*DD*DD;
    const float* b0  = procB + (size_t)(s*2+0)*DD;
    const float* b1p = procB + (size_t)(s*2+1)*DD;

    gemm_mfma_kernel<<<GG, 256, 0, stream>>>(hn, pP0h[s], pP0l[s], nullptr, dis, hbf, NN);
    gcn_agg_kernel<<<GA, 256, 0, stream>>>((const unsigned*)hbf, rowptr, csr, dis,
                                           b0, nullptr, nullptr, (unsigned*)ybf, 0);
    (void)hipMemsetAsync(bnsums, 0, 3*DD*4, stream);
    bn_stats_kernel<<<512, 256, 0, stream>>>(ybf, bnsums);
    bn_fold_kernel<<<16, 256, 0, stream>>>(bnsums, bnG + s*DD, bnB + s*DD, Wc2, pWfh, pWfl, cvec);
    gemm_bf_mfma_kernel<<<GG, 256, 0, stream>>>(ybf, pWfh, pWfl, cvec, dis, hbf, NN);
    gcn_agg_kernel<<<GA, 256, 0, stream>>>((const unsigned*)hbf, rowptr, csr, dis,
                                           b1p, hn, hn, nullptr, 1);
  }

  // decoder -> d_out (fp32)
  mlp_mfma_kernel<128, false><<<GN, 256, 0, stream>>>(hn, NN,
      pD1h, pD1l, db1, pD2h, pD2l, db2, pD3h, pD3l, db3, dlg, dlb, (float*)d_out,
      nullptr, nullptr);
}